// Round 11
// baseline (70.956 us; speedup 1.0000x reference)
//
#include <hip/hip_runtime.h>

constexpr int N_NODES   = 50000;
constexpr int N_EDGES   = 800000;
constexpr int D_FEAT    = 96;
constexpr int DIM_H     = 128;
constexpr int N_CLASSES = 10;

constexpr int SHIFT  = 8;                 // 256 nodes / bucket
constexpr int BNODES = 1 << SHIFT;
constexpr int NB     = (N_NODES + BNODES - 1) >> SHIFT;   // 196 buckets
constexpr int PREFW  = NB + 1;            // 197
constexpr int G      = 400;               // grid (co-resident: 8 waves/block, ~11 KB LDS)
constexpr int T      = 512;
constexpr int EPB    = N_EDGES / G;       // 2000 edges/block

static_assert(N_EDGES % G == 0, "exact edge split");
static_assert(N_NODES <= (1 << 16), "16-bit id packing");
static_assert(D_FEAT % 8 == 0, "8-lane row dot");

__device__ inline int wave_iscan(int v, int lane) {
#pragma unroll
    for (int off = 1; off < 64; off <<= 1) {
        int n = __shfl_up(v, off);
        if (lane >= off) v += n;
    }
    return v;
}

__device__ inline float wave_rsum(float v) {
#pragma unroll
    for (int off = 32; off > 0; off >>= 1) v += __shfl_down(v, off);
    return v;
}

// ---------------------------------------------------------------------------
// Fused persistent kernel (single dispatch).
// Phase A (all 400 blocks): y = x.a1 (8 lanes/row) + counting-sort of this
//   block's 2000 edges by dst>>8 via LDS; coalesced pair writeout; TRANSPOSED
//   prefix table pf_t[bucket*G + blk].
// Grid barrier: __syncthreads (drain all block stores) -> agent-scope ACQ_REL
//   arrival -> relaxed spin -> acquire -> __syncthreads.
// Phase B (blocks 0..195): block b assembles bucket b COMPLETELY (all 400
//   producer segments -> acc[256] in LDS) BEFORE the relu split (relu is
//   nonlinear: partial-aggregate splits are wrong — round 8/10 bug).
//   Ticketed last block reduces 196 partials + rank-1 tail -> out[10].
// ---------------------------------------------------------------------------
__global__ __launch_bounds__(T) void k_fused(
    const float* __restrict__ x,  const float* __restrict__ a1,
    const int* __restrict__ src,  const int* __restrict__ dst,
    const float* __restrict__ b1, const float* __restrict__ a2,
    const float* __restrict__ b2,
    float* __restrict__ y, unsigned* __restrict__ pairs,
    int* __restrict__ pf_t, float* __restrict__ PMpart,
    int* __restrict__ ctrs, float* __restrict__ out)
{
    __shared__ unsigned stage[EPB];          // 8 KB
    __shared__ int   hist[NB], run[NB], excl[NB];
    __shared__ int   wsum[T / 64];
    __shared__ float acc[BNODES];
    __shared__ float redp[8], redm[8], redcp[8], redcn[8];
    __shared__ int   islast;
    __shared__ float tval;

    const int tid  = threadIdx.x;
    const int lane = tid & 63, wid = tid >> 6;
    const int blk  = blockIdx.x;

    // ================= PHASE A =================
    if (tid < NB) hist[tid] = 0;

    // node dot: 8 lanes/row, 3 x float4/lane, grid-stride (2 iters)
    {
        const float4* av = reinterpret_cast<const float4*>(a1);
        const int sub = tid & 7;
        const float4 a0  = av[sub * 3 + 0];
        const float4 a1v = av[sub * 3 + 1];
        const float4 a2v = av[sub * 3 + 2];
        const int g0 = (blk * T + tid) >> 3;
        for (int r = g0; r < N_NODES; r += (G * T) / 8) {
            const float4* row =
                reinterpret_cast<const float4*>(x + (size_t)r * D_FEAT) + sub * 3;
            float4 v0 = row[0], v1 = row[1], v2 = row[2];
            float s = v0.x * a0.x + v0.y * a0.y + v0.z * a0.z + v0.w * a0.w
                    + v1.x * a1v.x + v1.y * a1v.y + v1.z * a1v.z + v1.w * a1v.w
                    + v2.x * a2v.x + v2.y * a2v.y + v2.z * a2v.z + v2.w * a2v.w;
            s += __shfl_xor(s, 1);
            s += __shfl_xor(s, 2);
            s += __shfl_xor(s, 4);
            if (sub == 0) y[r] = s;
        }
    }
    __syncthreads();

    // histogram of dst buckets
    const int e0 = blk * EPB;
    for (int j = tid; j < EPB; j += T)
        atomicAdd(&hist[((unsigned)dst[e0 + j]) >> SHIFT], 1);
    __syncthreads();

    // exclusive scan over NB bucket counts
    {
        int v   = (tid < NB) ? hist[tid] : 0;
        int inc = wave_iscan(v, lane);
        if (lane == 63) wsum[wid] = inc;
        __syncthreads();
        int woff = 0;
#pragma unroll
        for (int w = 0; w < T / 64; ++w) if (w < wid) woff += wsum[w];
        if (tid < NB) { int e = inc - v + woff; excl[tid] = e; run[tid] = e; }
    }
    __syncthreads();

    // transposed prefix table (coalesced reads in phase B); row NB = EPB sentinel
    if (tid < PREFW) pf_t[(size_t)tid * G + blk] = (tid < NB) ? excl[tid] : EPB;

    // scatter into binned LDS positions, then coalesced writeout
    for (int j = tid; j < EPB; j += T) {
        int d = dst[e0 + j];
        int s = src[e0 + j];
        int pos = atomicAdd(&run[((unsigned)d) >> SHIFT], 1);
        stage[pos] = ((unsigned)s << 16) | (unsigned)d;
    }
    __syncthreads();
    for (int j = tid; j < EPB; j += T)
        pairs[(size_t)blk * EPB + j] = stage[j];

    // ================= GRID BARRIER =================
    __syncthreads();   // all block stores drained before tid0 publishes arrival
    if (tid == 0) {
        __hip_atomic_fetch_add(&ctrs[0], 1, __ATOMIC_ACQ_REL,
                               __HIP_MEMORY_SCOPE_AGENT);
        while (__hip_atomic_load(&ctrs[0], __ATOMIC_RELAXED,
                                 __HIP_MEMORY_SCOPE_AGENT) < G)
            __builtin_amdgcn_s_sleep(2);
        (void)__hip_atomic_load(&ctrs[0], __ATOMIC_ACQUIRE,
                                __HIP_MEMORY_SCOPE_AGENT);
    }
    __syncthreads();

    // ================= PHASE B =================
    // one block per bucket; FULL bucket assembly before the relu split
    if (blk < NB) {
        const int b = blk;

        if (tid < BNODES) acc[tid] = 0.f;
        __syncthreads();

        // 400 producer segments, 1 thread per segment (threads 400..511 idle)
        if (tid < G) {
            const int t  = tid;
            const int st = pf_t[(size_t)b * G + t];
            const int en = pf_t[(size_t)(b + 1) * G + t];
            const unsigned* p0 = pairs + (size_t)t * EPB + st;
            const int n = en - st;
            for (int j = 0; j < n; ++j) {
                unsigned p = p0[j];
                atomicAdd(&acc[p & (BNODES - 1)], y[p >> 16]);
            }
        }
        __syncthreads();

        // relu-split partials for this bucket (s_n fully assembled)
        float pp = 0.f, mm = 0.f;
        if (tid < BNODES) {
            int gn = (b << SHIFT) + tid;
            if (gn < N_NODES) {
                float v = acc[tid];
                pp = fmaxf(v, 0.f);
                mm = fminf(v, 0.f);
            }
        }
        pp = wave_rsum(pp);
        mm = wave_rsum(mm);
        if (lane == 0) { redp[wid] = pp; redm[wid] = mm; }
        __syncthreads();
        if (tid == 0) {
            float tp = 0.f, tm = 0.f;
#pragma unroll
            for (int w = 0; w < 8; ++w) { tp += redp[w]; tm += redm[w]; }
            __hip_atomic_store(&PMpart[2 * b],     tp, __ATOMIC_RELAXED,
                               __HIP_MEMORY_SCOPE_AGENT);
            __hip_atomic_store(&PMpart[2 * b + 1], tm, __ATOMIC_RELAXED,
                               __HIP_MEMORY_SCOPE_AGENT);
            int t = __hip_atomic_fetch_add(&ctrs[1], 1, __ATOMIC_ACQ_REL,
                                           __HIP_MEMORY_SCOPE_AGENT);
            islast = (t == NB - 1);
        }
        __syncthreads();

        // ticketed last block: final reduction + rank-1 tail
        if (islast) {
            float P = 0.f, M = 0.f, cp = 0.f, cn = 0.f;
            if (tid < NB) {
                P = __hip_atomic_load(&PMpart[2 * tid],     __ATOMIC_RELAXED,
                                      __HIP_MEMORY_SCOPE_AGENT);
                M = __hip_atomic_load(&PMpart[2 * tid + 1], __ATOMIC_RELAXED,
                                      __HIP_MEMORY_SCOPE_AGENT);
            }
            if (tid < DIM_H) {
                float bv = b1[tid], pr = a2[tid] * bv;
                cp = (bv > 0.f) ? pr : 0.f;
                cn = (bv < 0.f) ? pr : 0.f;
            }
            P  = wave_rsum(P);
            M  = wave_rsum(M);
            cp = wave_rsum(cp);
            cn = wave_rsum(cn);
            __syncthreads();
            if (lane == 0) { redp[wid] = P; redm[wid] = M; redcp[wid] = cp; redcn[wid] = cn; }
            __syncthreads();
            if (tid == 0) {
                float sP = 0.f, sM = 0.f, sCP = 0.f, sCN = 0.f;
#pragma unroll
                for (int w = 0; w < 8; ++w) {
                    sP += redp[w]; sM += redm[w]; sCP += redcp[w]; sCN += redcn[w];
                }
                tval = sP * sCP + sM * sCN;
            }
            __syncthreads();
            if (tid < N_CLASSES) out[tid] = tval * b2[tid];
        }
    }
}

// ---------------------------------------------------------------------------
// fallback path (ws too small): device-scope atomic scatter
// ---------------------------------------------------------------------------
__global__ void fb_node_dot(const float* __restrict__ x, const float* __restrict__ a1,
                            float* __restrict__ y) {
    int i = blockIdx.x * blockDim.x + threadIdx.x;
    if (i >= N_NODES) return;
    const float4* row = reinterpret_cast<const float4*>(x + (size_t)i * D_FEAT);
    const float4* av  = reinterpret_cast<const float4*>(a1);
    float acc = 0.f;
#pragma unroll
    for (int k = 0; k < D_FEAT / 4; ++k) {
        float4 v = row[k], a = av[k];
        acc += v.x * a.x + v.y * a.y + v.z * a.z + v.w * a.w;
    }
    y[i] = acc;
}

__global__ void fb_scatter(const int* __restrict__ src, const int* __restrict__ dst,
                           const float* __restrict__ y, float* __restrict__ s) {
    int e = blockIdx.x * blockDim.x + threadIdx.x;
    if (e >= N_EDGES) return;
    atomicAdd(&s[dst[e]], y[src[e]]);
}

__global__ void fb_reduce(const float* __restrict__ s, float* __restrict__ PM) {
    float p = 0.f, m = 0.f;
    for (int i = blockIdx.x * blockDim.x + threadIdx.x; i < N_NODES;
         i += gridDim.x * blockDim.x) {
        float v = s[i];
        p += fmaxf(v, 0.f);
        m += fminf(v, 0.f);
    }
    p = wave_rsum(p);
    m = wave_rsum(m);
    __shared__ float lp[4], lm[4];
    int wid = threadIdx.x >> 6, lane = threadIdx.x & 63;
    if (lane == 0) { lp[wid] = p; lm[wid] = m; }
    __syncthreads();
    if (threadIdx.x == 0) {
        float tp = 0.f, tm = 0.f;
        for (int w = 0; w < (int)(blockDim.x >> 6); ++w) { tp += lp[w]; tm += lm[w]; }
        atomicAdd(&PM[0], tp);
        atomicAdd(&PM[1], tm);
    }
}

__global__ void fb_final(const float* __restrict__ b1, const float* __restrict__ a2,
                         const float* __restrict__ b2, const float* __restrict__ PM,
                         float* __restrict__ out) {
    int t = threadIdx.x;
    float bv = b1[t], prod = a2[t] * bv;
    float cp = (bv > 0.f) ? prod : 0.f;
    float cn = (bv < 0.f) ? prod : 0.f;
    cp = wave_rsum(cp);
    cn = wave_rsum(cn);
    __shared__ float scp[2], scn[2], tv;
    if ((t & 63) == 0) { scp[t >> 6] = cp; scn[t >> 6] = cn; }
    __syncthreads();
    if (t == 0) tv = PM[0] * (scp[0] + scp[1]) + PM[1] * (scn[0] + scn[1]);
    __syncthreads();
    if (t < N_CLASSES) out[t] = tv * b2[t];
}

extern "C" void kernel_launch(void* const* d_in, const int* in_sizes, int n_in,
                              void* d_out, int out_size, void* d_ws, size_t ws_size,
                              hipStream_t stream) {
    const float* x  = (const float*)d_in[0];
    const int*   ei = (const int*)d_in[1];   // [src(800000), dst(800000)]
    const float* a1 = (const float*)d_in[2];
    const float* b1 = (const float*)d_in[3];
    const float* a2 = (const float*)d_in[4];
    const float* b2 = (const float*)d_in[5];
    float* out = (float*)d_out;

    // ws layout: pairs u32[N_EDGES] | y f32[N_NODES] | pf_t i32[PREFW*G]
    //          | PMpart f32[2*NB] | ctrs i32[2]
    unsigned* pairs  = (unsigned*)d_ws;
    float*    y      = (float*)(pairs + N_EDGES);
    int*      pf_t   = (int*)(y + N_NODES);
    float*    PMpart = (float*)(pf_t + (size_t)PREFW * G);
    int*      ctrs   = (int*)(PMpart + 2 * NB);

    size_t need = (size_t)N_EDGES * 4 + (size_t)N_NODES * 4 +
                  (size_t)PREFW * G * 4 + (size_t)2 * NB * 4 + 8;

    if (ws_size >= need) {
        (void)hipMemsetAsync(ctrs, 0, 2 * sizeof(int), stream);  // barrier + ticket
        k_fused<<<G, T, 0, stream>>>(x, a1, ei, ei + N_EDGES, b1, a2, b2,
                                     y, pairs, pf_t, PMpart, ctrs, out);
    } else {
        float* yf = (float*)d_ws;
        float* s  = yf + N_NODES;
        float* PM = s + N_NODES;
        (void)hipMemsetAsync(s, 0, (N_NODES + 2) * sizeof(float), stream);
        fb_node_dot<<<(N_NODES + 255) / 256, 256, 0, stream>>>(x, a1, yf);
        fb_scatter<<<(N_EDGES + 255) / 256, 256, 0, stream>>>(ei, ei + N_EDGES, yf, s);
        fb_reduce<<<196, 256, 0, stream>>>(s, PM);
        fb_final<<<1, DIM_H, 0, stream>>>(b1, a2, b2, PM, out);
    }
}

// Round 12
// 35.742 us; speedup vs baseline: 1.9852x; 1.9852x over previous
//
#include <hip/hip_runtime.h>

constexpr int N_NODES   = 50000;
constexpr int N_EDGES   = 800000;
constexpr int D_FEAT    = 96;
constexpr int DIM_H     = 128;
constexpr int N_CLASSES = 10;

constexpr int SHIFT  = 8;                                 // 256 nodes / bucket
constexpr int BNODES = 1 << SHIFT;
constexpr int NB     = (N_NODES + BNODES - 1) >> SHIFT;   // 196 buckets
constexpr int NBLK1  = 256;                               // phase-1 blocks
constexpr int T1     = 1024;
constexpr int EPB    = N_EDGES / NBLK1;                   // 3125 edges/block
constexpr int CAP    = 8192;                              // slots per bucket region
constexpr int T2     = 512;

static_assert(N_NODES <= (1 << 16), "16-bit id packing");
static_assert(N_EDGES % NBLK1 == 0, "exact edge split");
static_assert(D_FEAT % 8 == 0, "8-lane row dot");
static_assert(CAP * NB >= N_EDGES, "capacity sanity");

__device__ inline int wave_iscan(int v, int lane) {
#pragma unroll
    for (int off = 1; off < 64; off <<= 1) {
        int n = __shfl_up(v, off);
        if (lane >= off) v += n;
    }
    return v;
}

__device__ inline float wave_rsum(float v) {
#pragma unroll
    for (int off = 32; off > 0; off >>= 1) v += __shfl_down(v, off);
    return v;
}

// ---------------------------------------------------------------------------
// K1 (256 blocks x 1024 thr): (a) y = x.a1 (8 lanes/row, coalesced);
// (b) counting-sort this block's 3125 edges by dst>>8 in LDS; (c) reserve a
// contiguous range in each bucket's GLOBAL region via one atomicAdd per
// (block,bucket) — 196 atomics/block; (d) copy grouped pairs to the bucket
// regions (runs of ~16 consecutive addresses -> mostly coalesced).
// Result: bucket b's pairs are CONTIGUOUS in bucketPairs[b*CAP ..], so
// phase 2 reads are fully coalesced (round-5's scattered walk removed).
// ---------------------------------------------------------------------------
__global__ __launch_bounds__(T1) void k_prep(
    const float* __restrict__ x, const float* __restrict__ a1,
    const int* __restrict__ src, const int* __restrict__ dst,
    float* __restrict__ y, unsigned* __restrict__ bucketPairs,
    int* __restrict__ ctl /* cursors[NB], ticket at [NB] */)
{
    __shared__ unsigned stage[EPB];            // 12.5 KB
    __shared__ int hist[NB], run[NB], excl[NB], baseg[NB];
    __shared__ int wsum[T1 / 64];
    const int tid  = threadIdx.x;
    const int lane = tid & 63, wid = tid >> 6;
    const int blk  = blockIdx.x;

    if (tid < NB) hist[tid] = 0;

    // ---- part A: node dot, 8 lanes per row, 3 x float4 per lane ----
    {
        const float4* av = reinterpret_cast<const float4*>(a1);
        const int sub = tid & 7;
        const float4 a0  = av[sub * 3 + 0];
        const float4 a1v = av[sub * 3 + 1];
        const float4 a2v = av[sub * 3 + 2];
        const int g0 = (blk * T1 + tid) >> 3;
        for (int r = g0; r < N_NODES; r += (NBLK1 * T1) / 8) {
            const float4* row =
                reinterpret_cast<const float4*>(x + (size_t)r * D_FEAT) + sub * 3;
            float4 v0 = row[0], v1 = row[1], v2 = row[2];
            float s = v0.x * a0.x + v0.y * a0.y + v0.z * a0.z + v0.w * a0.w
                    + v1.x * a1v.x + v1.y * a1v.y + v1.z * a1v.z + v1.w * a1v.w
                    + v2.x * a2v.x + v2.y * a2v.y + v2.z * a2v.z + v2.w * a2v.w;
            s += __shfl_xor(s, 1);
            s += __shfl_xor(s, 2);
            s += __shfl_xor(s, 4);
            if (sub == 0) y[r] = s;
        }
    }
    __syncthreads();

    // ---- histogram of dst buckets ----
    const int e0 = blk * EPB;
    for (int j = tid; j < EPB; j += T1)
        atomicAdd(&hist[((unsigned)dst[e0 + j]) >> SHIFT], 1);
    __syncthreads();

    // ---- exclusive scan (LDS grouping) + global slot reservation ----
    {
        int v   = (tid < NB) ? hist[tid] : 0;
        int inc = wave_iscan(v, lane);
        if (lane == 63) wsum[wid] = inc;
        __syncthreads();
        int woff = 0;
#pragma unroll
        for (int w = 0; w < T1 / 64; ++w) if (w < wid) woff += wsum[w];
        if (tid < NB) {
            int e = inc - v + woff;
            excl[tid] = e;
            run[tid]  = e;
            baseg[tid] = atomicAdd(&ctl[tid], v);   // reserve [base, base+v)
        }
    }
    __syncthreads();

    // ---- scatter into grouped LDS positions ----
    for (int j = tid; j < EPB; j += T1) {
        int d = dst[e0 + j];
        int s = src[e0 + j];
        int pos = atomicAdd(&run[((unsigned)d) >> SHIFT], 1);
        stage[pos] = ((unsigned)s << 16) | (unsigned)d;
    }
    __syncthreads();

    // ---- copy to global bucket regions (runs of ~16 -> coalesced chunks) ----
    for (int j = tid; j < EPB; j += T1) {
        unsigned p = stage[j];
        int b = (int)((p & 0xFFFFu) >> SHIFT);
        bucketPairs[(size_t)b * CAP + baseg[b] + (j - excl[b])] = p;
    }
}

// ---------------------------------------------------------------------------
// K2 (196 blocks x 512 thr): bucket b's pairs are contiguous — coalesced
// stream, LDS accumulate, relu-split partials; ticketed last block computes
// the final rank-1 output in-kernel.
// ---------------------------------------------------------------------------
__global__ __launch_bounds__(T2) void k_accum_final(
    const unsigned* __restrict__ bucketPairs, const int* __restrict__ ctl,
    const float* __restrict__ y, const float* __restrict__ b1,
    const float* __restrict__ a2, const float* __restrict__ b2,
    float* __restrict__ PMpart, int* __restrict__ ticket,
    float* __restrict__ out)
{
    __shared__ float acc[BNODES];
    __shared__ float redp[8], redm[8], redcp[8], redcn[8];
    __shared__ int   islast;
    __shared__ float tval;
    const int b    = blockIdx.x;
    const int tid  = threadIdx.x;
    const int lane = tid & 63, wid = tid >> 6;

    if (tid < BNODES) acc[tid] = 0.f;
    __syncthreads();

    // coalesced contiguous pair stream for this bucket
    {
        const int n = ctl[b];                       // final cursor == count
        const unsigned* p0 = bucketPairs + (size_t)b * CAP;
        for (int j = tid; j < n; j += T2) {
            unsigned p = p0[j];
            atomicAdd(&acc[(p & 0xFFFFu) & (BNODES - 1)], y[p >> 16]);
        }
    }
    __syncthreads();

    // relu-split partials for this bucket (complete s_n before the split)
    float pp = 0.f, mm = 0.f;
    if (tid < BNODES) {
        int gn = (b << SHIFT) + tid;
        if (gn < N_NODES) {
            float v = acc[tid];
            pp = fmaxf(v, 0.f);
            mm = fminf(v, 0.f);
        }
    }
    pp = wave_rsum(pp);
    mm = wave_rsum(mm);
    if (lane == 0) { redp[wid] = pp; redm[wid] = mm; }
    __syncthreads();
    if (tid == 0) {
        float tp = 0.f, tm = 0.f;
#pragma unroll
        for (int w = 0; w < 8; ++w) { tp += redp[w]; tm += redm[w]; }
        __hip_atomic_store(&PMpart[2 * b],     tp, __ATOMIC_RELAXED, __HIP_MEMORY_SCOPE_AGENT);
        __hip_atomic_store(&PMpart[2 * b + 1], tm, __ATOMIC_RELAXED, __HIP_MEMORY_SCOPE_AGENT);
        int t = __hip_atomic_fetch_add(ticket, 1, __ATOMIC_ACQ_REL, __HIP_MEMORY_SCOPE_AGENT);
        islast = (t == NB - 1);
    }
    __syncthreads();

    if (islast) {
        float P = 0.f, M = 0.f, cp = 0.f, cn = 0.f;
        if (tid < NB) {
            P = __hip_atomic_load(&PMpart[2 * tid],     __ATOMIC_RELAXED, __HIP_MEMORY_SCOPE_AGENT);
            M = __hip_atomic_load(&PMpart[2 * tid + 1], __ATOMIC_RELAXED, __HIP_MEMORY_SCOPE_AGENT);
        }
        if (tid < DIM_H) {
            float bv = b1[tid], pr = a2[tid] * bv;
            cp = (bv > 0.f) ? pr : 0.f;
            cn = (bv < 0.f) ? pr : 0.f;
        }
        P  = wave_rsum(P);
        M  = wave_rsum(M);
        cp = wave_rsum(cp);
        cn = wave_rsum(cn);
        __syncthreads();
        if (lane == 0) { redp[wid] = P; redm[wid] = M; redcp[wid] = cp; redcn[wid] = cn; }
        __syncthreads();
        if (tid == 0) {
            float sP = 0.f, sM = 0.f, sCP = 0.f, sCN = 0.f;
#pragma unroll
            for (int w = 0; w < 8; ++w) {
                sP += redp[w]; sM += redm[w]; sCP += redcp[w]; sCN += redcn[w];
            }
            tval = sP * sCP + sM * sCN;
        }
        __syncthreads();
        if (tid < N_CLASSES) out[tid] = tval * b2[tid];
    }
}

// ---------------------------------------------------------------------------
// fallback path (ws too small): device-scope atomic scatter
// ---------------------------------------------------------------------------
__global__ void fb_node_dot(const float* __restrict__ x, const float* __restrict__ a1,
                            float* __restrict__ y) {
    int i = blockIdx.x * blockDim.x + threadIdx.x;
    if (i >= N_NODES) return;
    const float4* row = reinterpret_cast<const float4*>(x + (size_t)i * D_FEAT);
    const float4* av  = reinterpret_cast<const float4*>(a1);
    float acc = 0.f;
#pragma unroll
    for (int k = 0; k < D_FEAT / 4; ++k) {
        float4 v = row[k], a = av[k];
        acc += v.x * a.x + v.y * a.y + v.z * a.z + v.w * a.w;
    }
    y[i] = acc;
}

__global__ void fb_scatter(const int* __restrict__ src, const int* __restrict__ dst,
                           const float* __restrict__ y, float* __restrict__ s) {
    int e = blockIdx.x * blockDim.x + threadIdx.x;
    if (e >= N_EDGES) return;
    atomicAdd(&s[dst[e]], y[src[e]]);
}

__global__ void fb_reduce(const float* __restrict__ s, float* __restrict__ PM) {
    float p = 0.f, m = 0.f;
    for (int i = blockIdx.x * blockDim.x + threadIdx.x; i < N_NODES;
         i += gridDim.x * blockDim.x) {
        float v = s[i];
        p += fmaxf(v, 0.f);
        m += fminf(v, 0.f);
    }
    p = wave_rsum(p);
    m = wave_rsum(m);
    __shared__ float lp[4], lm[4];
    int wid = threadIdx.x >> 6, lane = threadIdx.x & 63;
    if (lane == 0) { lp[wid] = p; lm[wid] = m; }
    __syncthreads();
    if (threadIdx.x == 0) {
        float tp = 0.f, tm = 0.f;
        for (int w = 0; w < (int)(blockDim.x >> 6); ++w) { tp += lp[w]; tm += lm[w]; }
        atomicAdd(&PM[0], tp);
        atomicAdd(&PM[1], tm);
    }
}

__global__ void fb_final(const float* __restrict__ b1, const float* __restrict__ a2,
                         const float* __restrict__ b2, const float* __restrict__ PM,
                         float* __restrict__ out) {
    int t = threadIdx.x;
    float bv = b1[t], prod = a2[t] * bv;
    float cp = (bv > 0.f) ? prod : 0.f;
    float cn = (bv < 0.f) ? prod : 0.f;
    cp = wave_rsum(cp);
    cn = wave_rsum(cn);
    __shared__ float scp[2], scn[2], tv;
    if ((t & 63) == 0) { scp[t >> 6] = cp; scn[t >> 6] = cn; }
    __syncthreads();
    if (t == 0) tv = PM[0] * (scp[0] + scp[1]) + PM[1] * (scn[0] + scn[1]);
    __syncthreads();
    if (t < N_CLASSES) out[t] = tv * b2[t];
}

extern "C" void kernel_launch(void* const* d_in, const int* in_sizes, int n_in,
                              void* d_out, int out_size, void* d_ws, size_t ws_size,
                              hipStream_t stream) {
    const float* x  = (const float*)d_in[0];
    const int*   ei = (const int*)d_in[1];   // [src(800000), dst(800000)]
    const float* a1 = (const float*)d_in[2];
    const float* b1 = (const float*)d_in[3];
    const float* a2 = (const float*)d_in[4];
    const float* b2 = (const float*)d_in[5];
    float* out = (float*)d_out;

    // ws layout: bucketPairs u32[NB*CAP] | y f32[N_NODES] | ctl i32[NB+1]
    //          | PMpart f32[2*NB]
    unsigned* bucketPairs = (unsigned*)d_ws;
    float*    y      = (float*)(bucketPairs + (size_t)NB * CAP);
    int*      ctl    = (int*)(y + N_NODES);            // cursors[0..NB-1], ticket[NB]
    float*    PMpart = (float*)(ctl + NB + 1);

    size_t need = (size_t)NB * CAP * 4 + (size_t)N_NODES * 4 +
                  (size_t)(NB + 1) * 4 + (size_t)2 * NB * 4;

    if (ws_size >= need) {
        (void)hipMemsetAsync(ctl, 0, (NB + 1) * sizeof(int), stream);
        k_prep<<<NBLK1, T1, 0, stream>>>(x, a1, ei, ei + N_EDGES, y, bucketPairs, ctl);
        k_accum_final<<<NB, T2, 0, stream>>>(bucketPairs, ctl, y, b1, a2, b2,
                                             PMpart, ctl + NB, out);
    } else {
        float* yf = (float*)d_ws;
        float* s  = yf + N_NODES;
        float* PM = s + N_NODES;
        (void)hipMemsetAsync(s, 0, (N_NODES + 2) * sizeof(float), stream);
        fb_node_dot<<<(N_NODES + 255) / 256, 256, 0, stream>>>(x, a1, yf);
        fb_scatter<<<(N_EDGES + 255) / 256, 256, 0, stream>>>(ei, ei + N_EDGES, yf, s);
        fb_reduce<<<196, 256, 0, stream>>>(s, PM);
        fb_final<<<1, DIM_H, 0, stream>>>(b1, a2, b2, PM, out);
    }
}

// Round 13
// 26.329 us; speedup vs baseline: 2.6949x; 1.3575x over previous
//
#include <hip/hip_runtime.h>

constexpr int N_NODES   = 50000;
constexpr int N_EDGES   = 800000;
constexpr int D_FEAT    = 96;
constexpr int DIM_H     = 128;
constexpr int N_CLASSES = 10;

constexpr int SHIFT  = 8;                                 // 256 nodes / bucket
constexpr int BNODES = 1 << SHIFT;
constexpr int NB     = (N_NODES + BNODES - 1) >> SHIFT;   // 196 buckets
constexpr int NBLK1  = 250;                               // phase-1 blocks
constexpr int T1     = 1024;
constexpr int EPB    = N_EDGES / NBLK1;                   // 3200 edges/block
constexpr int EPB4   = EPB / 4;                           // 800 uint4 per block
constexpr int PREFW  = NB + 1;                            // 197
constexpr int T2     = 512;

static_assert(N_NODES <= (1 << 16), "16-bit id packing");
static_assert(N_EDGES % NBLK1 == 0 && EPB % 4 == 0, "uint4 edge split");
static_assert(D_FEAT % 8 == 0, "8-lane row dot");

__device__ inline int wave_iscan(int v, int lane) {
#pragma unroll
    for (int off = 1; off < 64; off <<= 1) {
        int n = __shfl_up(v, off);
        if (lane >= off) v += n;
    }
    return v;
}

__device__ inline float wave_rsum(float v) {
#pragma unroll
    for (int off = 32; off > 0; off >>= 1) v += __shfl_down(v, off);
    return v;
}

// ---------------------------------------------------------------------------
// K1 (250 blocks x 1024 thr): (a) y = x.a1, 8 lanes/row (coalesced float4);
// (b) counting-sort this block's 3200 edges by dst>>8 via LDS, with ALL edge
// reads as uint4 (1 load / 4 edges; 2nd pass L1-warm); coalesced uint4
// writeout of binned (src<<16|dst) pairs + prefix table. No global atomics.
// ---------------------------------------------------------------------------
__global__ __launch_bounds__(T1) void k_prep(
    const float* __restrict__ x, const float* __restrict__ a1,
    const int* __restrict__ src, const int* __restrict__ dst,
    float* __restrict__ y, unsigned* __restrict__ pairs,
    int* __restrict__ prefg, int* __restrict__ ticket)
{
    __shared__ unsigned stage[EPB];            // 12.8 KB
    __shared__ int hist[NB], run[NB], excl[PREFW];
    __shared__ int wsum[T1 / 64];
    const int tid  = threadIdx.x;
    const int lane = tid & 63, wid = tid >> 6;
    const int blk  = blockIdx.x;

    if (blk == 0 && tid == 0)
        __hip_atomic_store(ticket, 0, __ATOMIC_RELAXED, __HIP_MEMORY_SCOPE_AGENT);

    if (tid < NB) hist[tid] = 0;

    // ---- part A: node dot, 8 lanes per row, 3 x float4 per lane ----
    {
        const float4* av = reinterpret_cast<const float4*>(a1);
        const int sub = tid & 7;
        const float4 a0  = av[sub * 3 + 0];
        const float4 a1v = av[sub * 3 + 1];
        const float4 a2v = av[sub * 3 + 2];
        const int g0 = (blk * T1 + tid) >> 3;
        for (int r = g0; r < N_NODES; r += (NBLK1 * T1) / 8) {
            const float4* row =
                reinterpret_cast<const float4*>(x + (size_t)r * D_FEAT) + sub * 3;
            float4 v0 = row[0], v1 = row[1], v2 = row[2];
            float s = v0.x * a0.x + v0.y * a0.y + v0.z * a0.z + v0.w * a0.w
                    + v1.x * a1v.x + v1.y * a1v.y + v1.z * a1v.z + v1.w * a1v.w
                    + v2.x * a2v.x + v2.y * a2v.y + v2.z * a2v.z + v2.w * a2v.w;
            s += __shfl_xor(s, 1);
            s += __shfl_xor(s, 2);
            s += __shfl_xor(s, 4);
            if (sub == 0) y[r] = s;
        }
    }
    __syncthreads();

    // ---- histogram of dst buckets (uint4 edge loads) ----
    const uint4* dst4 = reinterpret_cast<const uint4*>(dst + blk * EPB);
    const uint4* src4 = reinterpret_cast<const uint4*>(src + blk * EPB);
    if (tid < EPB4) {
        uint4 d = dst4[tid];
        atomicAdd(&hist[d.x >> SHIFT], 1);
        atomicAdd(&hist[d.y >> SHIFT], 1);
        atomicAdd(&hist[d.z >> SHIFT], 1);
        atomicAdd(&hist[d.w >> SHIFT], 1);
    }
    __syncthreads();

    // ---- exclusive scan over NB bucket counts ----
    {
        int v   = (tid < NB) ? hist[tid] : 0;
        int inc = wave_iscan(v, lane);
        if (lane == 63) wsum[wid] = inc;
        __syncthreads();
        int woff = 0;
#pragma unroll
        for (int w = 0; w < T1 / 64; ++w) if (w < wid) woff += wsum[w];
        if (tid < NB) { int e = inc - v + woff; excl[tid] = e; run[tid] = e; }
        if (tid == 0) {
            int t = 0;
#pragma unroll
            for (int w = 0; w < T1 / 64; ++w) t += wsum[w];
            excl[NB] = t;
        }
    }
    __syncthreads();
    if (tid < PREFW) prefg[blk * PREFW + tid] = excl[tid];

    // ---- scatter into binned LDS positions (uint4 re-read: L1-warm) ----
    if (tid < EPB4) {
        uint4 d = dst4[tid];
        uint4 s = src4[tid];
        int p;
        p = atomicAdd(&run[d.x >> SHIFT], 1); stage[p] = (s.x << 16) | d.x;
        p = atomicAdd(&run[d.y >> SHIFT], 1); stage[p] = (s.y << 16) | d.y;
        p = atomicAdd(&run[d.z >> SHIFT], 1); stage[p] = (s.z << 16) | d.z;
        p = atomicAdd(&run[d.w >> SHIFT], 1); stage[p] = (s.w << 16) | d.w;
    }
    __syncthreads();

    // ---- coalesced uint4 write-out of the block's region ----
    {
        const uint4* st4 = reinterpret_cast<const uint4*>(stage);
        uint4* out4 = reinterpret_cast<uint4*>(pairs + (size_t)blk * EPB);
        if (tid < EPB4) out4[tid] = st4[tid];
    }
}

// ---------------------------------------------------------------------------
// K2 (196 blocks x 512 thr): bucket accumulation in LDS. Two threads walk
// each producer segment (250 segs). Relu-split partials AFTER full bucket
// assembly; ticketed last block computes the final rank-1 output in-kernel.
// ---------------------------------------------------------------------------
__global__ __launch_bounds__(T2) void k_accum_final(
    const unsigned* __restrict__ pairs, const int* __restrict__ prefg,
    const float* __restrict__ y, const float* __restrict__ b1,
    const float* __restrict__ a2, const float* __restrict__ b2,
    float* __restrict__ PMpart, int* __restrict__ ticket,
    float* __restrict__ out)
{
    __shared__ float acc[BNODES];
    __shared__ int   soff[NBLK1], scnt[NBLK1];
    __shared__ float redp[8], redm[8], redcp[8], redcn[8];
    __shared__ int   islast;
    __shared__ float tval;
    const int b    = blockIdx.x;
    const int tid  = threadIdx.x;
    const int lane = tid & 63, wid = tid >> 6;

    if (tid < BNODES) acc[tid] = 0.f;
    if (tid < NBLK1) {
        int st = prefg[tid * PREFW + b];
        soff[tid] = st;
        scnt[tid] = prefg[tid * PREFW + b + 1] - st;
    }
    __syncthreads();

    // 512 threads -> 2 per segment (seg = tid>>1, half = tid&1); 250 segs
    {
        const int seg = tid >> 1, h = tid & 1;
        if (seg < NBLK1) {
            const int n = scnt[seg];
            const unsigned* p0 = pairs + (size_t)seg * EPB + soff[seg];
            for (int j = h; j < n; j += 2) {
                unsigned p = p0[j];
                atomicAdd(&acc[p & (BNODES - 1)], y[p >> 16]);
            }
        }
    }
    __syncthreads();

    // relu-split partials (complete s_n before split)
    float pp = 0.f, mm = 0.f;
    if (tid < BNODES) {
        int gn = (b << SHIFT) + tid;
        if (gn < N_NODES) {
            float v = acc[tid];
            pp = fmaxf(v, 0.f);
            mm = fminf(v, 0.f);
        }
    }
    pp = wave_rsum(pp);
    mm = wave_rsum(mm);
    if (lane == 0) { redp[wid] = pp; redm[wid] = mm; }
    __syncthreads();
    if (tid == 0) {
        float tp = 0.f, tm = 0.f;
#pragma unroll
        for (int w = 0; w < 8; ++w) { tp += redp[w]; tm += redm[w]; }
        __hip_atomic_store(&PMpart[2 * b],     tp, __ATOMIC_RELAXED, __HIP_MEMORY_SCOPE_AGENT);
        __hip_atomic_store(&PMpart[2 * b + 1], tm, __ATOMIC_RELAXED, __HIP_MEMORY_SCOPE_AGENT);
        int t = __hip_atomic_fetch_add(ticket, 1, __ATOMIC_ACQ_REL, __HIP_MEMORY_SCOPE_AGENT);
        islast = (t == NB - 1);
    }
    __syncthreads();

    if (islast) {
        float P = 0.f, M = 0.f, cp = 0.f, cn = 0.f;
        if (tid < NB) {
            P = __hip_atomic_load(&PMpart[2 * tid],     __ATOMIC_RELAXED, __HIP_MEMORY_SCOPE_AGENT);
            M = __hip_atomic_load(&PMpart[2 * tid + 1], __ATOMIC_RELAXED, __HIP_MEMORY_SCOPE_AGENT);
        }
        if (tid < DIM_H) {
            float bv = b1[tid], pr = a2[tid] * bv;
            cp = (bv > 0.f) ? pr : 0.f;
            cn = (bv < 0.f) ? pr : 0.f;
        }
        P  = wave_rsum(P);
        M  = wave_rsum(M);
        cp = wave_rsum(cp);
        cn = wave_rsum(cn);
        __syncthreads();
        if (lane == 0) { redp[wid] = P; redm[wid] = M; redcp[wid] = cp; redcn[wid] = cn; }
        __syncthreads();
        if (tid == 0) {
            float sP = 0.f, sM = 0.f, sCP = 0.f, sCN = 0.f;
#pragma unroll
            for (int w = 0; w < 8; ++w) {
                sP += redp[w]; sM += redm[w]; sCP += redcp[w]; sCN += redcn[w];
            }
            tval = sP * sCP + sM * sCN;
        }
        __syncthreads();
        if (tid < N_CLASSES) out[tid] = tval * b2[tid];
    }
}

// ---------------------------------------------------------------------------
// fallback path (ws too small): device-scope atomic scatter
// ---------------------------------------------------------------------------
__global__ void fb_node_dot(const float* __restrict__ x, const float* __restrict__ a1,
                            float* __restrict__ y) {
    int i = blockIdx.x * blockDim.x + threadIdx.x;
    if (i >= N_NODES) return;
    const float4* row = reinterpret_cast<const float4*>(x + (size_t)i * D_FEAT);
    const float4* av  = reinterpret_cast<const float4*>(a1);
    float acc = 0.f;
#pragma unroll
    for (int k = 0; k < D_FEAT / 4; ++k) {
        float4 v = row[k], a = av[k];
        acc += v.x * a.x + v.y * a.y + v.z * a.z + v.w * a.w;
    }
    y[i] = acc;
}

__global__ void fb_scatter(const int* __restrict__ src, const int* __restrict__ dst,
                           const float* __restrict__ y, float* __restrict__ s) {
    int e = blockIdx.x * blockDim.x + threadIdx.x;
    if (e >= N_EDGES) return;
    atomicAdd(&s[dst[e]], y[src[e]]);
}

__global__ void fb_reduce(const float* __restrict__ s, float* __restrict__ PM) {
    float p = 0.f, m = 0.f;
    for (int i = blockIdx.x * blockDim.x + threadIdx.x; i < N_NODES;
         i += gridDim.x * blockDim.x) {
        float v = s[i];
        p += fmaxf(v, 0.f);
        m += fminf(v, 0.f);
    }
    p = wave_rsum(p);
    m = wave_rsum(m);
    __shared__ float lp[4], lm[4];
    int wid = threadIdx.x >> 6, lane = threadIdx.x & 63;
    if (lane == 0) { lp[wid] = p; lm[wid] = m; }
    __syncthreads();
    if (threadIdx.x == 0) {
        float tp = 0.f, tm = 0.f;
        for (int w = 0; w < (int)(blockDim.x >> 6); ++w) { tp += lp[w]; tm += lm[w]; }
        atomicAdd(&PM[0], tp);
        atomicAdd(&PM[1], tm);
    }
}

__global__ void fb_final(const float* __restrict__ b1, const float* __restrict__ a2,
                         const float* __restrict__ b2, const float* __restrict__ PM,
                         float* __restrict__ out) {
    int t = threadIdx.x;
    float bv = b1[t], prod = a2[t] * bv;
    float cp = (bv > 0.f) ? prod : 0.f;
    float cn = (bv < 0.f) ? prod : 0.f;
    cp = wave_rsum(cp);
    cn = wave_rsum(cn);
    __shared__ float scp[2], scn[2], tv;
    if ((t & 63) == 0) { scp[t >> 6] = cp; scn[t >> 6] = cn; }
    __syncthreads();
    if (t == 0) tv = PM[0] * (scp[0] + scp[1]) + PM[1] * (scn[0] + scn[1]);
    __syncthreads();
    if (t < N_CLASSES) out[t] = tv * b2[t];
}

extern "C" void kernel_launch(void* const* d_in, const int* in_sizes, int n_in,
                              void* d_out, int out_size, void* d_ws, size_t ws_size,
                              hipStream_t stream) {
    const float* x  = (const float*)d_in[0];
    const int*   ei = (const int*)d_in[1];   // [src(800000), dst(800000)]
    const float* a1 = (const float*)d_in[2];
    const float* b1 = (const float*)d_in[3];
    const float* a2 = (const float*)d_in[4];
    const float* b2 = (const float*)d_in[5];
    float* out = (float*)d_out;

    // ws layout: pairs u32[N_EDGES] | y f32[N_NODES] | prefg i32[NBLK1*PREFW]
    //          | PMpart f32[2*NB] | ticket i32
    unsigned* pairs  = (unsigned*)d_ws;
    float*    y      = (float*)(pairs + N_EDGES);
    int*      prefg  = (int*)(y + N_NODES);
    float*    PMpart = (float*)(prefg + (size_t)NBLK1 * PREFW);
    int*      ticket = (int*)(PMpart + 2 * NB);

    size_t need = (size_t)N_EDGES * 4 + (size_t)N_NODES * 4 +
                  (size_t)NBLK1 * PREFW * 4 + (size_t)2 * NB * 4 + 4;

    if (ws_size >= need) {
        k_prep<<<NBLK1, T1, 0, stream>>>(x, a1, ei, ei + N_EDGES, y, pairs, prefg, ticket);
        k_accum_final<<<NB, T2, 0, stream>>>(pairs, prefg, y, b1, a2, b2,
                                             PMpart, ticket, out);
    } else {
        float* yf = (float*)d_ws;
        float* s  = yf + N_NODES;
        float* PM = s + N_NODES;
        (void)hipMemsetAsync(s, 0, (N_NODES + 2) * sizeof(float), stream);
        fb_node_dot<<<(N_NODES + 255) / 256, 256, 0, stream>>>(x, a1, yf);
        fb_scatter<<<(N_EDGES + 255) / 256, 256, 0, stream>>>(ei, ei + N_EDGES, yf, s);
        fb_reduce<<<196, 256, 0, stream>>>(s, PM);
        fb_final<<<1, DIM_H, 0, stream>>>(b1, a2, b2, PM, out);
    }
}

// Round 14
// 26.251 us; speedup vs baseline: 2.7030x; 1.0030x over previous
//
#include <hip/hip_runtime.h>

constexpr int N_NODES   = 50000;
constexpr int N_EDGES   = 800000;
constexpr int D_FEAT    = 96;
constexpr int DIM_H     = 128;
constexpr int N_CLASSES = 10;

constexpr int SHIFT  = 8;                                 // 256 nodes / bucket
constexpr int BNODES = 1 << SHIFT;
constexpr int NB     = (N_NODES + BNODES - 1) >> SHIFT;   // 196 buckets
constexpr int NBLK1  = 250;                               // phase-1 blocks
constexpr int T1     = 1024;
constexpr int EPB    = N_EDGES / NBLK1;                   // 3200 edges/block
constexpr int EPB4   = EPB / 4;                           // 800 uint4 per block
constexpr int PREFW  = NB + 1;                            // 197
constexpr int T2     = 512;

static_assert(N_NODES <= (1 << 16), "16-bit id packing");
static_assert(N_EDGES % NBLK1 == 0 && EPB % 4 == 0, "uint4 edge split");
static_assert(D_FEAT % 8 == 0, "8-lane row dot");

__device__ inline int wave_iscan(int v, int lane) {
#pragma unroll
    for (int off = 1; off < 64; off <<= 1) {
        int n = __shfl_up(v, off);
        if (lane >= off) v += n;
    }
    return v;
}

__device__ inline float wave_rsum(float v) {
#pragma unroll
    for (int off = 32; off > 0; off >>= 1) v += __shfl_down(v, off);
    return v;
}

// ---------------------------------------------------------------------------
// K1 (250 blocks x 1024 thr): (a) y = x.a1, 8 lanes/row (coalesced float4);
// (b) counting-sort this block's 3200 edges by dst>>8 via LDS, with ALL edge
// reads as uint4 (1 load / 4 edges; 2nd pass L1-warm); coalesced uint4
// writeout of binned (src<<16|dst) pairs + prefix table. No global atomics.
// (unchanged from round-13 champion)
// ---------------------------------------------------------------------------
__global__ __launch_bounds__(T1) void k_prep(
    const float* __restrict__ x, const float* __restrict__ a1,
    const int* __restrict__ src, const int* __restrict__ dst,
    float* __restrict__ y, unsigned* __restrict__ pairs,
    int* __restrict__ prefg, int* __restrict__ ticket)
{
    __shared__ unsigned stage[EPB];            // 12.8 KB
    __shared__ int hist[NB], run[NB], excl[PREFW];
    __shared__ int wsum[T1 / 64];
    const int tid  = threadIdx.x;
    const int lane = tid & 63, wid = tid >> 6;
    const int blk  = blockIdx.x;

    if (blk == 0 && tid == 0)
        __hip_atomic_store(ticket, 0, __ATOMIC_RELAXED, __HIP_MEMORY_SCOPE_AGENT);

    if (tid < NB) hist[tid] = 0;

    // ---- part A: node dot, 8 lanes per row, 3 x float4 per lane ----
    {
        const float4* av = reinterpret_cast<const float4*>(a1);
        const int sub = tid & 7;
        const float4 a0  = av[sub * 3 + 0];
        const float4 a1v = av[sub * 3 + 1];
        const float4 a2v = av[sub * 3 + 2];
        const int g0 = (blk * T1 + tid) >> 3;
        for (int r = g0; r < N_NODES; r += (NBLK1 * T1) / 8) {
            const float4* row =
                reinterpret_cast<const float4*>(x + (size_t)r * D_FEAT) + sub * 3;
            float4 v0 = row[0], v1 = row[1], v2 = row[2];
            float s = v0.x * a0.x + v0.y * a0.y + v0.z * a0.z + v0.w * a0.w
                    + v1.x * a1v.x + v1.y * a1v.y + v1.z * a1v.z + v1.w * a1v.w
                    + v2.x * a2v.x + v2.y * a2v.y + v2.z * a2v.z + v2.w * a2v.w;
            s += __shfl_xor(s, 1);
            s += __shfl_xor(s, 2);
            s += __shfl_xor(s, 4);
            if (sub == 0) y[r] = s;
        }
    }
    __syncthreads();

    // ---- histogram of dst buckets (uint4 edge loads) ----
    const uint4* dst4 = reinterpret_cast<const uint4*>(dst + blk * EPB);
    const uint4* src4 = reinterpret_cast<const uint4*>(src + blk * EPB);
    if (tid < EPB4) {
        uint4 d = dst4[tid];
        atomicAdd(&hist[d.x >> SHIFT], 1);
        atomicAdd(&hist[d.y >> SHIFT], 1);
        atomicAdd(&hist[d.z >> SHIFT], 1);
        atomicAdd(&hist[d.w >> SHIFT], 1);
    }
    __syncthreads();

    // ---- exclusive scan over NB bucket counts ----
    {
        int v   = (tid < NB) ? hist[tid] : 0;
        int inc = wave_iscan(v, lane);
        if (lane == 63) wsum[wid] = inc;
        __syncthreads();
        int woff = 0;
#pragma unroll
        for (int w = 0; w < T1 / 64; ++w) if (w < wid) woff += wsum[w];
        if (tid < NB) { int e = inc - v + woff; excl[tid] = e; run[tid] = e; }
        if (tid == 0) {
            int t = 0;
#pragma unroll
            for (int w = 0; w < T1 / 64; ++w) t += wsum[w];
            excl[NB] = t;
        }
    }
    __syncthreads();
    if (tid < PREFW) prefg[blk * PREFW + tid] = excl[tid];

    // ---- scatter into binned LDS positions (uint4 re-read: L1-warm) ----
    if (tid < EPB4) {
        uint4 d = dst4[tid];
        uint4 s = src4[tid];
        int p;
        p = atomicAdd(&run[d.x >> SHIFT], 1); stage[p] = (s.x << 16) | d.x;
        p = atomicAdd(&run[d.y >> SHIFT], 1); stage[p] = (s.y << 16) | d.y;
        p = atomicAdd(&run[d.z >> SHIFT], 1); stage[p] = (s.z << 16) | d.z;
        p = atomicAdd(&run[d.w >> SHIFT], 1); stage[p] = (s.w << 16) | d.w;
    }
    __syncthreads();

    // ---- coalesced uint4 write-out of the block's region ----
    {
        const uint4* st4 = reinterpret_cast<const uint4*>(stage);
        uint4* out4 = reinterpret_cast<uint4*>(pairs + (size_t)blk * EPB);
        if (tid < EPB4) out4[tid] = st4[tid];
    }
}

// ---------------------------------------------------------------------------
// K2 (196 blocks x 512 thr): bucket accumulation in LDS, 2 threads per
// producer segment. NEW: 4-deep batched walk — 4 independent pair loads,
// then 4 independent y gathers, then 4 LDS atomics (dependent-chain depth
// per thread drops 8 -> 2). Relu split AFTER full bucket assembly; ticketed
// last block computes the final rank-1 output in-kernel.
// ---------------------------------------------------------------------------
__global__ __launch_bounds__(T2) void k_accum_final(
    const unsigned* __restrict__ pairs, const int* __restrict__ prefg,
    const float* __restrict__ y, const float* __restrict__ b1,
    const float* __restrict__ a2, const float* __restrict__ b2,
    float* __restrict__ PMpart, int* __restrict__ ticket,
    float* __restrict__ out)
{
    __shared__ float acc[BNODES];
    __shared__ int   soff[NBLK1], scnt[NBLK1];
    __shared__ float redp[8], redm[8], redcp[8], redcn[8];
    __shared__ int   islast;
    __shared__ float tval;
    const int b    = blockIdx.x;
    const int tid  = threadIdx.x;
    const int lane = tid & 63, wid = tid >> 6;

    if (tid < BNODES) acc[tid] = 0.f;
    if (tid < NBLK1) {
        int st = prefg[tid * PREFW + b];
        soff[tid] = st;
        scnt[tid] = prefg[tid * PREFW + b + 1] - st;
    }
    __syncthreads();

    // 512 threads -> 2 per segment; 4-deep batched MLP walk
    {
        const int seg = tid >> 1, h = tid & 1;
        if (seg < NBLK1) {
            const int n = scnt[seg];
            const unsigned* p0 = pairs + (size_t)seg * EPB + soff[seg];
            int j = h;
            for (; j + 6 < n; j += 8) {
                unsigned q0 = p0[j], q1 = p0[j + 2], q2 = p0[j + 4], q3 = p0[j + 6];
                float y0 = y[q0 >> 16], y1 = y[q1 >> 16];
                float y2 = y[q2 >> 16], y3 = y[q3 >> 16];
                atomicAdd(&acc[q0 & (BNODES - 1)], y0);
                atomicAdd(&acc[q1 & (BNODES - 1)], y1);
                atomicAdd(&acc[q2 & (BNODES - 1)], y2);
                atomicAdd(&acc[q3 & (BNODES - 1)], y3);
            }
            for (; j < n; j += 2) {
                unsigned p = p0[j];
                atomicAdd(&acc[p & (BNODES - 1)], y[p >> 16]);
            }
        }
    }
    __syncthreads();

    // relu-split partials (complete s_n before split)
    float pp = 0.f, mm = 0.f;
    if (tid < BNODES) {
        int gn = (b << SHIFT) + tid;
        if (gn < N_NODES) {
            float v = acc[tid];
            pp = fmaxf(v, 0.f);
            mm = fminf(v, 0.f);
        }
    }
    pp = wave_rsum(pp);
    mm = wave_rsum(mm);
    if (lane == 0) { redp[wid] = pp; redm[wid] = mm; }
    __syncthreads();
    if (tid == 0) {
        float tp = 0.f, tm = 0.f;
#pragma unroll
        for (int w = 0; w < 8; ++w) { tp += redp[w]; tm += redm[w]; }
        __hip_atomic_store(&PMpart[2 * b],     tp, __ATOMIC_RELAXED, __HIP_MEMORY_SCOPE_AGENT);
        __hip_atomic_store(&PMpart[2 * b + 1], tm, __ATOMIC_RELAXED, __HIP_MEMORY_SCOPE_AGENT);
        int t = __hip_atomic_fetch_add(ticket, 1, __ATOMIC_ACQ_REL, __HIP_MEMORY_SCOPE_AGENT);
        islast = (t == NB - 1);
    }
    __syncthreads();

    if (islast) {
        float P = 0.f, M = 0.f, cp = 0.f, cn = 0.f;
        if (tid < NB) {
            P = __hip_atomic_load(&PMpart[2 * tid],     __ATOMIC_RELAXED, __HIP_MEMORY_SCOPE_AGENT);
            M = __hip_atomic_load(&PMpart[2 * tid + 1], __ATOMIC_RELAXED, __HIP_MEMORY_SCOPE_AGENT);
        }
        if (tid < DIM_H) {
            float bv = b1[tid], pr = a2[tid] * bv;
            cp = (bv > 0.f) ? pr : 0.f;
            cn = (bv < 0.f) ? pr : 0.f;
        }
        P  = wave_rsum(P);
        M  = wave_rsum(M);
        cp = wave_rsum(cp);
        cn = wave_rsum(cn);
        __syncthreads();
        if (lane == 0) { redp[wid] = P; redm[wid] = M; redcp[wid] = cp; redcn[wid] = cn; }
        __syncthreads();
        if (tid == 0) {
            float sP = 0.f, sM = 0.f, sCP = 0.f, sCN = 0.f;
#pragma unroll
            for (int w = 0; w < 8; ++w) {
                sP += redp[w]; sM += redm[w]; sCP += redcp[w]; sCN += redcn[w];
            }
            tval = sP * sCP + sM * sCN;
        }
        __syncthreads();
        if (tid < N_CLASSES) out[tid] = tval * b2[tid];
    }
}

// ---------------------------------------------------------------------------
// fallback path (ws too small): device-scope atomic scatter
// ---------------------------------------------------------------------------
__global__ void fb_node_dot(const float* __restrict__ x, const float* __restrict__ a1,
                            float* __restrict__ y) {
    int i = blockIdx.x * blockDim.x + threadIdx.x;
    if (i >= N_NODES) return;
    const float4* row = reinterpret_cast<const float4*>(x + (size_t)i * D_FEAT);
    const float4* av  = reinterpret_cast<const float4*>(a1);
    float acc = 0.f;
#pragma unroll
    for (int k = 0; k < D_FEAT / 4; ++k) {
        float4 v = row[k], a = av[k];
        acc += v.x * a.x + v.y * a.y + v.z * a.z + v.w * a.w;
    }
    y[i] = acc;
}

__global__ void fb_scatter(const int* __restrict__ src, const int* __restrict__ dst,
                           const float* __restrict__ y, float* __restrict__ s) {
    int e = blockIdx.x * blockDim.x + threadIdx.x;
    if (e >= N_EDGES) return;
    atomicAdd(&s[dst[e]], y[src[e]]);
}

__global__ void fb_reduce(const float* __restrict__ s, float* __restrict__ PM) {
    float p = 0.f, m = 0.f;
    for (int i = blockIdx.x * blockDim.x + threadIdx.x; i < N_NODES;
         i += gridDim.x * blockDim.x) {
        float v = s[i];
        p += fmaxf(v, 0.f);
        m += fminf(v, 0.f);
    }
    p = wave_rsum(p);
    m = wave_rsum(m);
    __shared__ float lp[4], lm[4];
    int wid = threadIdx.x >> 6, lane = threadIdx.x & 63;
    if (lane == 0) { lp[wid] = p; lm[wid] = m; }
    __syncthreads();
    if (threadIdx.x == 0) {
        float tp = 0.f, tm = 0.f;
        for (int w = 0; w < (int)(blockDim.x >> 6); ++w) { tp += lp[w]; tm += lm[w]; }
        atomicAdd(&PM[0], tp);
        atomicAdd(&PM[1], tm);
    }
}

__global__ void fb_final(const float* __restrict__ b1, const float* __restrict__ a2,
                         const float* __restrict__ b2, const float* __restrict__ PM,
                         float* __restrict__ out) {
    int t = threadIdx.x;
    float bv = b1[t], prod = a2[t] * bv;
    float cp = (bv > 0.f) ? prod : 0.f;
    float cn = (bv < 0.f) ? prod : 0.f;
    cp = wave_rsum(cp);
    cn = wave_rsum(cn);
    __shared__ float scp[2], scn[2], tv;
    if ((t & 63) == 0) { scp[t >> 6] = cp; scn[t >> 6] = cn; }
    __syncthreads();
    if (t == 0) tv = PM[0] * (scp[0] + scp[1]) + PM[1] * (scn[0] + scn[1]);
    __syncthreads();
    if (t < N_CLASSES) out[t] = tv * b2[t];
}

extern "C" void kernel_launch(void* const* d_in, const int* in_sizes, int n_in,
                              void* d_out, int out_size, void* d_ws, size_t ws_size,
                              hipStream_t stream) {
    const float* x  = (const float*)d_in[0];
    const int*   ei = (const int*)d_in[1];   // [src(800000), dst(800000)]
    const float* a1 = (const float*)d_in[2];
    const float* b1 = (const float*)d_in[3];
    const float* a2 = (const float*)d_in[4];
    const float* b2 = (const float*)d_in[5];
    float* out = (float*)d_out;

    // ws layout: pairs u32[N_EDGES] | y f32[N_NODES] | prefg i32[NBLK1*PREFW]
    //          | PMpart f32[2*NB] | ticket i32
    unsigned* pairs  = (unsigned*)d_ws;
    float*    y      = (float*)(pairs + N_EDGES);
    int*      prefg  = (int*)(y + N_NODES);
    float*    PMpart = (float*)(prefg + (size_t)NBLK1 * PREFW);
    int*      ticket = (int*)(PMpart + 2 * NB);

    size_t need = (size_t)N_EDGES * 4 + (size_t)N_NODES * 4 +
                  (size_t)NBLK1 * PREFW * 4 + (size_t)2 * NB * 4 + 4;

    if (ws_size >= need) {
        k_prep<<<NBLK1, T1, 0, stream>>>(x, a1, ei, ei + N_EDGES, y, pairs, prefg, ticket);
        k_accum_final<<<NB, T2, 0, stream>>>(pairs, prefg, y, b1, a2, b2,
                                             PMpart, ticket, out);
    } else {
        float* yf = (float*)d_ws;
        float* s  = yf + N_NODES;
        float* PM = s + N_NODES;
        (void)hipMemsetAsync(s, 0, (N_NODES + 2) * sizeof(float), stream);
        fb_node_dot<<<(N_NODES + 255) / 256, 256, 0, stream>>>(x, a1, yf);
        fb_scatter<<<(N_EDGES + 255) / 256, 256, 0, stream>>>(ei, ei + N_EDGES, yf, s);
        fb_reduce<<<196, 256, 0, stream>>>(s, PM);
        fb_final<<<1, DIM_H, 0, stream>>>(b1, a2, b2, PM, out);
    }
}